// Round 1
// baseline (576.227 us; speedup 1.0000x reference)
//
#include <hip/hip_runtime.h>
#include <math.h>

// Problem constants (from reference)
#define PB_B      16
#define PB_H      16
#define PB_D      128
#define PB_BLOCK  16
#define PB_BPS    128     // blocks per sequence
#define PB_MAXS   2048    // BLOCK * BLOCKS_PER_SEQ
#define PB_HD     (PB_H * PB_D)   // 2048 floats per slot row

#define NT        512     // threads per block (8 waves)
#define NSG       (NT / 32)  // 16 position groups of 32 lanes

__global__ __launch_bounds__(NT) void paged_attn_decode(
    const float* __restrict__ Q,      // [B,H,D]
    const float* __restrict__ Knew,   // [B,H,D]
    const float* __restrict__ Vnew,   // [B,H,D]
    const float* __restrict__ Kc,     // [NUM_BLOCKS, BLOCK, H, D]
    const float* __restrict__ Vc,     // [NUM_BLOCKS, BLOCK, H, D]
    const float* __restrict__ cosT,   // [MAXS, 1, D]
    const float* __restrict__ sinT,   // [MAXS, 1, D]
    const float* __restrict__ mask,   // [B, MAXS]
    const int*   __restrict__ cache_len,   // [B]
    const int*   __restrict__ fetch_slots, // [B, BPS]
    float*       __restrict__ out)    // [B,H,D]
{
    const int bh  = blockIdx.x;       // 0..255
    const int b   = bh >> 4;
    const int h   = bh & 15;
    const int tid = threadIdx.x;
    const int cl  = cache_len[b];     // new token position; valid s: 0..cl
    const float scale = 0.08838834764831845f;  // 1/sqrt(128)

    __shared__ float sScore[PB_MAXS];          // 8 KB
    __shared__ int   sSlots[PB_BPS];           // 0.5 KB
    __shared__ float sQr[PB_D];                // RoPE'd Q
    __shared__ float sKr[PB_D];                // RoPE'd new K
    __shared__ float sRedM[NT / 64];
    __shared__ float sRedS[NT / 64];
    __shared__ float4 sAcc[NSG][32];           // 8 KB

    // --- load block table row for this sequence ---
    if (tid < PB_BPS) sSlots[tid] = fetch_slots[b * PB_BPS + tid];

    // --- RoPE on Q and new K at position cl (llama half-dim convention) ---
    if (tid < PB_D) {
        const float c = cosT[(size_t)cl * PB_D + tid];
        const float s = sinT[(size_t)cl * PB_D + tid];
        const float q = Q[(size_t)bh * PB_D + tid];
        const float k = Knew[(size_t)bh * PB_D + tid];
        const float qrot = (tid < 64) ? -Q[(size_t)bh * PB_D + tid + 64]
                                      :  Q[(size_t)bh * PB_D + tid - 64];
        const float krot = (tid < 64) ? -Knew[(size_t)bh * PB_D + tid + 64]
                                      :  Knew[(size_t)bh * PB_D + tid - 64];
        sQr[tid] = q * c + qrot * s;
        sKr[tid] = k * c + krot * s;
    }
    __syncthreads();

    const int dsub = tid & 31;   // 0..31 : owns dims [dsub*4, dsub*4+4)
    const int ssub = tid >> 5;   // 0..15 : position group
    const float4 qv = ((const float4*)sQr)[dsub];
    const float* mrow = mask + (size_t)b * PB_MAXS;

    // --- Pass A: scores for cached positions s in [0, cl) ---
    #pragma unroll 4
    for (int s = ssub; s < cl; s += NSG) {
        const int slot = sSlots[s >> 4] * PB_BLOCK + (s & 15);
        const float4 kv = ((const float4*)(Kc + (size_t)slot * PB_HD + (size_t)h * PB_D))[dsub];
        float dot = qv.x * kv.x + qv.y * kv.y + qv.z * kv.z + qv.w * kv.w;
        #pragma unroll
        for (int off = 16; off >= 1; off >>= 1) dot += __shfl_xor(dot, off);
        if (dsub == 0) sScore[s] = dot * scale + mrow[s];
    }
    // new token score at s == cl (uses RoPE'd new K)
    if (tid < 32) {
        const float4 kv = ((const float4*)sKr)[dsub];
        float dot = qv.x * kv.x + qv.y * kv.y + qv.z * kv.z + qv.w * kv.w;
        #pragma unroll
        for (int off = 16; off >= 1; off >>= 1) dot += __shfl_xor(dot, off);
        if (dsub == 0) sScore[cl] = dot * scale + mrow[cl];
    }
    __syncthreads();

    // --- softmax: block max over sScore[0..cl] ---
    float lm = -INFINITY;
    for (int s = tid; s <= cl; s += NT) lm = fmaxf(lm, sScore[s]);
    #pragma unroll
    for (int off = 32; off >= 1; off >>= 1) lm = fmaxf(lm, __shfl_xor(lm, off));
    if ((tid & 63) == 0) sRedM[tid >> 6] = lm;
    __syncthreads();
    float m = sRedM[0];
    #pragma unroll
    for (int w = 1; w < NT / 64; ++w) m = fmaxf(m, sRedM[w]);

    // exp in place + block sum
    float ls = 0.0f;
    for (int s = tid; s <= cl; s += NT) {
        const float p = __expf(sScore[s] - m);
        sScore[s] = p;
        ls += p;
    }
    #pragma unroll
    for (int off = 32; off >= 1; off >>= 1) ls += __shfl_xor(ls, off);
    if ((tid & 63) == 0) sRedS[tid >> 6] = ls;
    __syncthreads();   // also makes all sScore exp-writes visible
    float sum = 0.0f;
    #pragma unroll
    for (int w = 0; w < NT / 64; ++w) sum += sRedS[w];

    // --- Pass B: out = sum_s p[s] * V[s] ---
    float4 acc = make_float4(0.f, 0.f, 0.f, 0.f);
    #pragma unroll 4
    for (int s = ssub; s < cl; s += NSG) {
        const int slot = sSlots[s >> 4] * PB_BLOCK + (s & 15);
        const float4 vv = ((const float4*)(Vc + (size_t)slot * PB_HD + (size_t)h * PB_D))[dsub];
        const float p = sScore[s];
        acc.x += p * vv.x; acc.y += p * vv.y; acc.z += p * vv.z; acc.w += p * vv.w;
    }
    if (ssub == 0) {  // new token contribution (un-RoPE'd new V, per reference)
        const float p = sScore[cl];
        const float4 vv = ((const float4*)(Vnew + (size_t)bh * PB_D))[dsub];
        acc.x += p * vv.x; acc.y += p * vv.y; acc.z += p * vv.z; acc.w += p * vv.w;
    }
    sAcc[ssub][dsub] = acc;
    __syncthreads();

    if (tid < 32) {
        float4 a = sAcc[0][tid];
        #pragma unroll
        for (int g = 1; g < NSG; ++g) {
            const float4 t = sAcc[g][tid];
            a.x += t.x; a.y += t.y; a.z += t.z; a.w += t.w;
        }
        const float inv = 1.0f / sum;
        a.x *= inv; a.y *= inv; a.z *= inv; a.w *= inv;
        ((float4*)(out + (size_t)bh * PB_D))[tid] = a;
    }
}

extern "C" void kernel_launch(void* const* d_in, const int* in_sizes, int n_in,
                              void* d_out, int out_size, void* d_ws, size_t ws_size,
                              hipStream_t stream) {
    const float* Q     = (const float*)d_in[0];
    const float* Knew  = (const float*)d_in[1];
    const float* Vnew  = (const float*)d_in[2];
    const float* Kc    = (const float*)d_in[3];
    const float* Vc    = (const float*)d_in[4];
    const float* cosT  = (const float*)d_in[5];
    const float* sinT  = (const float*)d_in[6];
    const float* mask  = (const float*)d_in[7];
    // d_in[8] = input_length (unused, ==1)
    const int* cache_len   = (const int*)d_in[9];
    // d_in[10] = save_slots (unused: written slot == position cache_len[b] of seq b)
    const int* fetch_slots = (const int*)d_in[11];
    // d_in[12] = max_s (compile-time constant here)
    float* out = (float*)d_out;

    paged_attn_decode<<<PB_B * PB_H, NT, 0, stream>>>(
        Q, Knew, Vnew, Kc, Vc, cosT, sinT, mask, cache_len, fetch_slots, out);
}

// Round 4
// 499.608 us; speedup vs baseline: 1.1534x; 1.1534x over previous
//
#include <hip/hip_runtime.h>
#include <math.h>

// Problem constants (from reference)
#define PB_B      16
#define PB_H      16
#define PB_BH     (PB_B * PB_H)
#define PB_D      128
#define PB_BLOCK  16
#define PB_BPS    128     // blocks per sequence
#define PB_MAXS   2048
#define PB_HD     (PB_H * PB_D)   // 2048 floats per slot row

#define NSPLIT    8       // position splits per (b,h)  -> grid = 2048 WGs
#define NT1       256     // threads per split block (4 waves)
#define NGRP      (NT1 / 32)      // 8 position groups of 32 lanes
#define MAXCHUNK  256     // ceil(2047/8) = 256 max positions per split

// ---------------- split kernel: partial softmax-attention per chunk ----------
__global__ __launch_bounds__(NT1) void pa_split(
    const float* __restrict__ Q,
    const float* __restrict__ Knew,
    const float* __restrict__ Vnew,
    const float* __restrict__ Kc,
    const float* __restrict__ Vc,
    const float* __restrict__ cosT,
    const float* __restrict__ sinT,
    const float* __restrict__ mask,
    const int*   __restrict__ cache_len,
    const int*   __restrict__ fetch_slots,
    float*       __restrict__ wsAcc,   // [BH*NSPLIT*D] unnormalized partial out
    float*       __restrict__ wsM,     // [BH*NSPLIT] local max
    float*       __restrict__ wsL)     // [BH*NSPLIT] local expsum
{
    const int gid = blockIdx.x;             // bh*NSPLIT + k
    const int k   = gid & (NSPLIT - 1);
    const int bh  = gid >> 3;
    const int b   = bh >> 4;
    const int h   = bh & 15;
    const int tid = threadIdx.x;
    const int cl  = cache_len[b];
    const int n_total = cl + 1;             // valid positions 0..cl
    const int chunk = (n_total + NSPLIT - 1) / NSPLIT;
    const int lo = k * chunk;
    const int hi = min(lo + chunk, n_total);
    const int n  = hi - lo;
    const float scale = 0.08838834764831845f;  // 1/sqrt(128)

    float* accOut = wsAcc + (size_t)gid * PB_D;

    if (n <= 0) {   // empty split: neutral element
        if (tid < PB_D) accOut[tid] = 0.0f;
        if (tid == 0) { wsM[gid] = -INFINITY; wsL[gid] = 0.0f; }
        return;
    }

    __shared__ float sScore[MAXCHUNK];         // 1 KB
    __shared__ int   sSlots[PB_BPS];           // 0.5 KB
    __shared__ float sQr[PB_D];
    __shared__ float sKr[PB_D];
    __shared__ float sRed[NT1 / 64];
    __shared__ float sRedS[NT1 / 64];
    __shared__ float4 sAcc[NGRP][32];          // 4 KB

    if (tid < PB_BPS) sSlots[tid] = fetch_slots[b * PB_BPS + tid];

    // RoPE on Q (and new K) at position cl, llama half-dim convention
    if (tid < PB_D) {
        const float c = cosT[(size_t)cl * PB_D + tid];
        const float s = sinT[(size_t)cl * PB_D + tid];
        const float q = Q[(size_t)bh * PB_D + tid];
        const float kk = Knew[(size_t)bh * PB_D + tid];
        const float qrot = (tid < 64) ? -Q[(size_t)bh * PB_D + tid + 64]
                                      :  Q[(size_t)bh * PB_D + tid - 64];
        const float krot = (tid < 64) ? -Knew[(size_t)bh * PB_D + tid + 64]
                                      :  Knew[(size_t)bh * PB_D + tid - 64];
        sQr[tid] = q * c + qrot * s;
        sKr[tid] = kk * c + krot * s;
    }
    __syncthreads();

    const int dsub = tid & 31;   // owns dims [dsub*4, dsub*4+4)
    const int grp  = tid >> 5;   // position group 0..7
    const float4 qv = ((const float4*)sQr)[dsub];
    const float* mrow = mask + (size_t)b * PB_MAXS;

    // --- Pass A: scores for cached positions in [lo, min(hi,cl)) ---
    const int sc_end = min(hi, cl);
    #pragma unroll 4
    for (int s = lo + grp; s < sc_end; s += NGRP) {
        const int slot = sSlots[s >> 4] * PB_BLOCK + (s & 15);
        const float4 kv = ((const float4*)(Kc + (size_t)slot * PB_HD + (size_t)h * PB_D))[dsub];
        float dot = qv.x * kv.x + qv.y * kv.y + qv.z * kv.z + qv.w * kv.w;
        #pragma unroll
        for (int off = 16; off >= 1; off >>= 1) dot += __shfl_xor(dot, off);
        if (dsub == 0) sScore[s - lo] = dot * scale + mrow[s];
    }
    // new-token position cl (RoPE'd new K), only in the split that owns it
    if (cl >= lo && cl < hi && tid < 32) {
        const float4 kv = ((const float4*)sKr)[dsub];
        float dot = qv.x * kv.x + qv.y * kv.y + qv.z * kv.z + qv.w * kv.w;
        #pragma unroll
        for (int off = 16; off >= 1; off >>= 1) dot += __shfl_xor(dot, off);
        if (dsub == 0) sScore[cl - lo] = dot * scale + mrow[cl];
    }
    __syncthreads();

    // --- local softmax over sScore[0..n) ---
    float lm = -INFINITY;
    for (int i = tid; i < n; i += NT1) lm = fmaxf(lm, sScore[i]);
    #pragma unroll
    for (int off = 32; off >= 1; off >>= 1) lm = fmaxf(lm, __shfl_xor(lm, off));
    if ((tid & 63) == 0) sRed[tid >> 6] = lm;
    __syncthreads();
    float m = fmaxf(fmaxf(sRed[0], sRed[1]), fmaxf(sRed[2], sRed[3]));

    float ls = 0.0f;
    for (int i = tid; i < n; i += NT1) {
        const float p = __expf(sScore[i] - m);
        sScore[i] = p;
        ls += p;
    }
    #pragma unroll
    for (int off = 32; off >= 1; off >>= 1) ls += __shfl_xor(ls, off);
    if ((tid & 63) == 0) sRedS[tid >> 6] = ls;
    __syncthreads();   // also publishes sScore exp values
    const float lsum = sRedS[0] + sRedS[1] + sRedS[2] + sRedS[3];

    // --- Pass B: partial out = sum_s p[s] * V[s] (unnormalized) ---
    float4 acc = make_float4(0.f, 0.f, 0.f, 0.f);
    #pragma unroll 4
    for (int s = lo + grp; s < sc_end; s += NGRP) {
        const int slot = sSlots[s >> 4] * PB_BLOCK + (s & 15);
        const float4 vv = ((const float4*)(Vc + (size_t)slot * PB_HD + (size_t)h * PB_D))[dsub];
        const float p = sScore[s - lo];
        acc.x += p * vv.x; acc.y += p * vv.y; acc.z += p * vv.z; acc.w += p * vv.w;
    }
    if (cl >= lo && cl < hi && grp == 0) {   // new token uses un-RoPE'd Vnew
        const float p = sScore[cl - lo];
        const float4 vv = ((const float4*)(Vnew + (size_t)bh * PB_D))[dsub];
        acc.x += p * vv.x; acc.y += p * vv.y; acc.z += p * vv.z; acc.w += p * vv.w;
    }
    sAcc[grp][dsub] = acc;
    __syncthreads();

    if (tid < 32) {
        float4 a = sAcc[0][tid];
        #pragma unroll
        for (int g = 1; g < NGRP; ++g) {
            const float4 t = sAcc[g][tid];
            a.x += t.x; a.y += t.y; a.z += t.z; a.w += t.w;
        }
        ((float4*)accOut)[tid] = a;
    }
    if (tid == 0) { wsM[gid] = m; wsL[gid] = lsum; }
}

// ---------------- combine kernel: merge NSPLIT partials per (b,h) ------------
__global__ __launch_bounds__(PB_D) void pa_combine(
    const float* __restrict__ wsAcc,
    const float* __restrict__ wsM,
    const float* __restrict__ wsL,
    float*       __restrict__ out)
{
    const int bh = blockIdx.x;
    const int d  = threadIdx.x;

    float mv[NSPLIT];
    float M = -INFINITY;
    #pragma unroll
    for (int i = 0; i < NSPLIT; ++i) {
        mv[i] = wsM[bh * NSPLIT + i];
        M = fmaxf(M, mv[i]);
    }
    float denom = 0.0f;
    float w[NSPLIT];
    #pragma unroll
    for (int i = 0; i < NSPLIT; ++i) {
        w[i] = __expf(mv[i] - M);
        denom += w[i] * wsL[bh * NSPLIT + i];
    }
    float o = 0.0f;
    #pragma unroll
    for (int i = 0; i < NSPLIT; ++i)
        o += w[i] * wsAcc[(size_t)(bh * NSPLIT + i) * PB_D + d];
    out[(size_t)bh * PB_D + d] = o / denom;
}

extern "C" void kernel_launch(void* const* d_in, const int* in_sizes, int n_in,
                              void* d_out, int out_size, void* d_ws, size_t ws_size,
                              hipStream_t stream) {
    const float* Q     = (const float*)d_in[0];
    const float* Knew  = (const float*)d_in[1];
    const float* Vnew  = (const float*)d_in[2];
    const float* Kc    = (const float*)d_in[3];
    const float* Vc    = (const float*)d_in[4];
    const float* cosT  = (const float*)d_in[5];
    const float* sinT  = (const float*)d_in[6];
    const float* mask  = (const float*)d_in[7];
    const int* cache_len   = (const int*)d_in[9];
    const int* fetch_slots = (const int*)d_in[11];
    float* out = (float*)d_out;

    float* wsAcc = (float*)d_ws;                              // BH*NSPLIT*D floats
    float* wsM   = wsAcc + (size_t)PB_BH * NSPLIT * PB_D;     // BH*NSPLIT
    float* wsL   = wsM + PB_BH * NSPLIT;                      // BH*NSPLIT

    pa_split<<<PB_BH * NSPLIT, NT1, 0, stream>>>(
        Q, Knew, Vnew, Kc, Vc, cosT, sinT, mask, cache_len, fetch_slots,
        wsAcc, wsM, wsL);
    pa_combine<<<PB_BH, PB_D, 0, stream>>>(wsAcc, wsM, wsL, out);
}